// Round 1
// baseline (1907.778 us; speedup 1.0000x reference)
//
#include <hip/hip_runtime.h>
#include <hip/hip_bf16.h>
#include <math.h>

#define BATCH 4096
#define POOL 32
#define TTAB 26
#define MSPA 64
#define NROWS 200000
#define NFEAT 27            // 1 + TTAB
#define TFW (NFEAT * MSPA)  // 1728 floats per batch row of Tfeat
#define RW 416              // padded row width of R (415 used)

// ---------------- embedding gather + pool ----------------
// One wave64 per (table, batch) pair. lane = embedding dim (64 floats = 256B
// per row -> one coalesced transaction per row load). Indices loaded by the
// first 32 lanes once, broadcast via shfl.
__global__ __launch_bounds__(256) void gather_pool_kernel(
    const float* __restrict__ tables, const int* __restrict__ lS_i,
    float* __restrict__ Tfeat) {
  int gid = blockIdx.x * 256 + threadIdx.x;
  int wave = gid >> 6;
  int lane = threadIdx.x & 63;
  if (wave >= TTAB * BATCH) return;
  int t = wave / BATCH;
  int b = wave - t * BATCH;
  const int* idx = lS_i + (size_t)t * BATCH * POOL + (size_t)b * POOL;
  const float* tab = tables + (size_t)t * NROWS * MSPA;
  int my = (lane < POOL) ? idx[lane] : 0;
  float acc = 0.f;
#pragma unroll
  for (int p = 0; p < POOL; ++p) {
    int r = __shfl(my, p);
    acc += tab[(size_t)r * MSPA + lane];
  }
  Tfeat[(size_t)b * TFW + (size_t)(1 + t) * MSPA + lane] = acc;
}

// ---------------- tiled fp32 GEMM: C = [relu](A * W^T + bias) -------------
// A: M x K (lda), W: N x K (row-major, as in torch Linear), C: M x N (ldc).
// 64x64 tile, BK=32, 256 threads, 4x4 microtile per thread.
// LDS stored transposed [BK][dim+pad] so inner loop reads are float4.
__global__ __launch_bounds__(256) void gemm_wt_bias(
    const float* __restrict__ A, int lda, const float* __restrict__ W,
    const float* __restrict__ bias, float* __restrict__ C, int ldc, int M,
    int N, int K, int do_relu) {
  const int BM = 64, BN = 64, BK = 32;
  __shared__ __align__(16) float As[BK][BM + 4];  // [32][68]
  __shared__ __align__(16) float Ws[BK][BN + 4];
  int tid = threadIdx.x;
  int tx = tid & 15, ty = tid >> 4;
  int bm = blockIdx.y, bn = blockIdx.x;
  float acc[4][4] = {};
  for (int k0 = 0; k0 < K; k0 += BK) {
#pragma unroll
    for (int e = tid; e < BM * BK; e += 256) {
      int row = e >> 5, col = e & 31;
      int gk = k0 + col;
      As[col][row] = (gk < K) ? A[(size_t)(bm * BM + row) * lda + gk] : 0.f;
    }
#pragma unroll
    for (int e = tid; e < BN * BK; e += 256) {
      int row = e >> 5, col = e & 31;
      int gk = k0 + col;
      int gn = bn * BN + row;
      Ws[col][row] = (gk < K && gn < N) ? W[(size_t)gn * K + gk] : 0.f;
    }
    __syncthreads();
#pragma unroll
    for (int kk = 0; kk < BK; ++kk) {
      float4 a4 = *(const float4*)&As[kk][ty * 4];
      float4 b4 = *(const float4*)&Ws[kk][tx * 4];
      float av[4] = {a4.x, a4.y, a4.z, a4.w};
      float bv[4] = {b4.x, b4.y, b4.z, b4.w};
#pragma unroll
      for (int i = 0; i < 4; ++i)
#pragma unroll
        for (int j = 0; j < 4; ++j) acc[i][j] = fmaf(av[i], bv[j], acc[i][j]);
    }
    __syncthreads();
  }
  int colbase = bn * BN + tx * 4;
  if (colbase + 3 < N) {
    float4 bb = *(const float4*)&bias[colbase];
    float bv[4] = {bb.x, bb.y, bb.z, bb.w};
#pragma unroll
    for (int i = 0; i < 4; ++i) {
      int row = bm * BM + ty * 4 + i;
      float ov[4];
#pragma unroll
      for (int j = 0; j < 4; ++j) {
        float v = acc[i][j] + bv[j];
        if (do_relu) v = fmaxf(v, 0.f);
        ov[j] = v;
      }
      *(float4*)&C[(size_t)row * ldc + colbase] =
          make_float4(ov[0], ov[1], ov[2], ov[3]);
    }
  }
}

// ---------------- pairwise interaction ----------------
// One block per batch row. Tfeat row (27x64) staged in LDS padded to 65
// floats/row (kills the stride-64 bank conflict). Writes R = [x | lower-tri].
__global__ __launch_bounds__(256) void interact_kernel(
    const float* __restrict__ Tfeat, float* __restrict__ R) {
  __shared__ float sm[NFEAT * 65];
  int b = blockIdx.x;
  int tid = threadIdx.x;
  const float* rowp = Tfeat + (size_t)b * TFW;
  for (int e = tid; e < TFW; e += 256) {
    int r = e >> 6, d = e & 63;
    sm[r * 65 + d] = rowp[e];
  }
  __syncthreads();
  if (tid < MSPA) R[(size_t)b * RW + tid] = sm[tid];
  for (int p = tid; p < 351; p += 256) {
    // invert p = i*(i-1)/2 + j, j < i
    int i = (int)((1.f + sqrtf((float)(8 * p + 1))) * 0.5f);
    while (i * (i - 1) / 2 > p) --i;
    while ((i + 1) * i / 2 <= p) ++i;
    int j = p - i * (i - 1) / 2;
    const float* ri = sm + i * 65;
    const float* rj = sm + j * 65;
    float s = 0.f;
#pragma unroll
    for (int d = 0; d < MSPA; ++d) s = fmaf(ri[d], rj[d], s);
    R[(size_t)b * RW + MSPA + p] = s;
  }
}

// ---------------- top MLP final layer (N=1) + sigmoid ----------------
__global__ __launch_bounds__(256) void top_final_kernel(
    const float* __restrict__ t2, const float* __restrict__ w,
    const float* __restrict__ bias, float* __restrict__ out) {
  int gid = blockIdx.x * 256 + threadIdx.x;
  int wid = gid >> 6, lane = threadIdx.x & 63;
  if (wid >= BATCH) return;
  const float* rowp = t2 + (size_t)wid * 256;
  float s = 0.f;
#pragma unroll
  for (int k = 0; k < 4; ++k) s = fmaf(rowp[lane + 64 * k], w[lane + 64 * k], s);
#pragma unroll
  for (int off = 32; off > 0; off >>= 1) s += __shfl_down(s, off);
  if (lane == 0) out[wid] = 1.f / (1.f + expf(-(s + bias[0])));
}

extern "C" void kernel_launch(void* const* d_in, const int* in_sizes, int n_in,
                              void* d_out, int out_size, void* d_ws,
                              size_t ws_size, hipStream_t stream) {
  const float* dense_x = (const float*)d_in[0];
  // d_in[1] = lS_o (unused)
  const int* lS_i = (const int*)d_in[2];
  const float* emb = (const float*)d_in[3];
  const float* bw0 = (const float*)d_in[4];
  const float* bb0 = (const float*)d_in[5];
  const float* bw1 = (const float*)d_in[6];
  const float* bb1 = (const float*)d_in[7];
  const float* bw2 = (const float*)d_in[8];
  const float* bb2 = (const float*)d_in[9];
  const float* tw0 = (const float*)d_in[10];
  const float* tb0 = (const float*)d_in[11];
  const float* tw1 = (const float*)d_in[12];
  const float* tb1 = (const float*)d_in[13];
  const float* tw2 = (const float*)d_in[14];
  const float* tb2 = (const float*)d_in[15];
  float* out = (float*)d_out;

  float* ws = (float*)d_ws;
  float* Tfeat = ws;                             // 4096*1728 floats
  float* act1 = Tfeat + (size_t)BATCH * TFW;     // 4096*512 (also top t1)
  float* act2 = act1 + (size_t)BATCH * 512;      // 4096*256 (also top t2)
  float* R = act2 + (size_t)BATCH * 256;         // 4096*416

  dim3 blk(256);
  // embedding gather+pool -> Tfeat[:,1:27,:]
  int nwaves = TTAB * BATCH;
  gather_pool_kernel<<<dim3((nwaves * 64 + 255) / 256), blk, 0, stream>>>(
      emb, lS_i, Tfeat);
  // bottom MLP
  gemm_wt_bias<<<dim3(8, 64), blk, 0, stream>>>(dense_x, 13, bw0, bb0, act1,
                                                512, BATCH, 512, 13, 1);
  gemm_wt_bias<<<dim3(4, 64), blk, 0, stream>>>(act1, 512, bw1, bb1, act2, 256,
                                                BATCH, 256, 512, 1);
  gemm_wt_bias<<<dim3(1, 64), blk, 0, stream>>>(act2, 256, bw2, bb2, Tfeat,
                                                TFW, BATCH, 64, 256, 1);
  // interaction -> R
  interact_kernel<<<dim3(BATCH), blk, 0, stream>>>(Tfeat, R);
  // top MLP
  gemm_wt_bias<<<dim3(8, 64), blk, 0, stream>>>(R, RW, tw0, tb0, act1, 512,
                                                BATCH, 512, 415, 1);
  gemm_wt_bias<<<dim3(4, 64), blk, 0, stream>>>(act1, 512, tw1, tb1, act2, 256,
                                                BATCH, 256, 512, 1);
  top_final_kernel<<<dim3((BATCH * 64 + 255) / 256), blk, 0, stream>>>(
      act2, tw2, tb2, out);
}